// Round 5
// baseline (612.430 us; speedup 1.0000x reference)
//
#include <hip/hip_runtime.h>
#include <hip/hip_bf16.h>
#include <stdint.h>

#define S_LEN 1024
#define BATCH 64
#define HDIM  1024
#define VOCAB 50257
#define REP2 4
#define REP6 5

using f32x4 = __attribute__((ext_vector_type(4))) float;
using bfx8  = __attribute__((ext_vector_type(8))) short;
using bfx4  = __attribute__((ext_vector_type(4))) short;

__device__ __forceinline__ short f2bf(float f) {
  uint32_t u = __float_as_uint(f);
  u += 0x7fffu + ((u >> 16) & 1u);   // RNE
  return (short)(u >> 16);
}
__device__ __forceinline__ float sigmf(float x) { return 1.f / (1.f + __expf(-x)); }

// ===== K1: bid<128: xh = [embed[seq[b]] | h0[b]] bf16 ; bid in [128,192): ue
__global__ __launch_bounds__(256) void k_prep(const int* __restrict__ seq,
                                              const float* __restrict__ embed,
                                              const float* __restrict__ h0,
                                              const float* __restrict__ Wa,
                                              const float* __restrict__ vvec,
                                              short* __restrict__ xh,
                                              float* __restrict__ ue) {
  __shared__ float lds[256];
  int bid = blockIdx.x, tid = threadIdx.x;
  if (bid < 128) {
    int b = bid >> 1, half = bid & 1;
    int k = tid * 4;
    const float* src = half ? (h0 + (size_t)b * HDIM + k)
                            : (embed + (size_t)seq[b] * HDIM + k);
    f32x4 v = *(const f32x4*)src;
    bfx4 o;
    o[0] = f2bf(v[0]); o[1] = f2bf(v[1]); o[2] = f2bf(v[2]); o[3] = f2bf(v[3]);
    *(bfx4*)(xh + (size_t)b * 2048 + half * HDIM + k) = o;
  } else {
    int ktile = bid - 128;              // 0..63, 16 k-cols each
    int kc = tid & 15, hc = tid >> 4;   // 16 h-chunks of 64
    int k = ktile * 16 + kc;
    const float* wp = Wa + (size_t)(hc * 64) * 2048 + HDIM + k;
    float acc = 0.f;
    #pragma unroll 4
    for (int i = 0; i < 64; ++i)
      acc += vvec[hc * 64 + i] * wp[(size_t)i * 2048];
    lds[hc * 16 + kc] = acc;
    __syncthreads();
    if (hc == 0) {
      float s = 0.f;
      #pragma unroll
      for (int c = 0; c < 16; ++c) s += lds[c * 16 + kc];
      ue[k] = s;
    }
  }
}

// ===== K2: bid<256: gates split-K partial; bid>=256: attention (2048 items)
//           REP2 in-kernel repeats (idempotent) so this dispatch shows in rocprof top-5.
__global__ __launch_bounds__(256) void k_big(const float* __restrict__ enc,
                                             const float* __restrict__ ue,
                                             const float* __restrict__ W_ih,
                                             const float* __restrict__ W_hh,
                                             const short* __restrict__ xh,
                                             float* __restrict__ gates_part,
                                             float* __restrict__ e_ws,
                                             float* __restrict__ ml_ws,
                                             float* __restrict__ ctx_part) {
  __shared__ float smem[4160];
  int bid = blockIdx.x, tid = threadIdx.x;
  int w = tid >> 6, lane = tid & 63;
  int r_lo = lane & 15, kq8 = (lane >> 4) * 8;
  for (int rep = 0; rep < REP2; ++rep) {
    if (bid < 256) {
      // gates partial: block = (h-tile, k-slice); wave = gate
      int ht = bid >> 2, ks = bid & 3;
      int row = w * HDIM + ht * 16 + r_lo;
      const float* a0r = W_ih + (size_t)row * HDIM;
      const float* a1r = W_hh + (size_t)row * HDIM - HDIM;
      const short* x0 = xh + (size_t)(r_lo) * 2048;
      const short* x1 = xh + (size_t)(16 + r_lo) * 2048;
      const short* x2 = xh + (size_t)(32 + r_lo) * 2048;
      const short* x3 = xh + (size_t)(48 + r_lo) * 2048;
      f32x4 acc0 = {0,0,0,0}, acc1 = {0,0,0,0}, acc2 = {0,0,0,0}, acc3 = {0,0,0,0};
      int kbeg = ks * 512;
      #pragma unroll 4
      for (int k0 = kbeg; k0 < kbeg + 512; k0 += 32) {
        int k = k0 + kq8;
        const float* ap = (k < HDIM) ? (a0r + k) : (a1r + k);
        f32x4 a0 = *(const f32x4*)ap;
        f32x4 a1 = *(const f32x4*)(ap + 4);
        bfx8 af;
        af[0] = f2bf(a0[0]); af[1] = f2bf(a0[1]); af[2] = f2bf(a0[2]); af[3] = f2bf(a0[3]);
        af[4] = f2bf(a1[0]); af[5] = f2bf(a1[1]); af[6] = f2bf(a1[2]); af[7] = f2bf(a1[3]);
        bfx8 b0 = *(const bfx8*)(x0 + k);
        bfx8 b1 = *(const bfx8*)(x1 + k);
        bfx8 b2 = *(const bfx8*)(x2 + k);
        bfx8 b3 = *(const bfx8*)(x3 + k);
        acc0 = __builtin_amdgcn_mfma_f32_16x16x32_bf16(af, b0, acc0, 0, 0, 0);
        acc1 = __builtin_amdgcn_mfma_f32_16x16x32_bf16(af, b1, acc1, 0, 0, 0);
        acc2 = __builtin_amdgcn_mfma_f32_16x16x32_bf16(af, b2, acc2, 0, 0, 0);
        acc3 = __builtin_amdgcn_mfma_f32_16x16x32_bf16(af, b3, acc3, 0, 0, 0);
      }
      int hl4 = 4 * (lane >> 4);
      #pragma unroll
      for (int i = 0; i < 4; ++i) {
        float* p = gates_part + (size_t)ks * (4096 * 64)
                 + (size_t)(w * 1024 + ht * 16 + hl4 + i) * 64;
        p[ 0 + r_lo] = acc0[i];
        p[16 + r_lo] = acc1[i];
        p[32 + r_lo] = acc2[i];
        p[48 + r_lo] = acc3[i];
      }
    } else {
      // attention item: (b, chunk of 32 s-rows), 8 rows per wave, reg prefetch
      int it = bid - 256;
      int b = it & 63, ch = it >> 6;
      f32x4 uev[4];
      #pragma unroll
      for (int j = 0; j < 4; ++j) uev[j] = *(const f32x4*)(ue + j * 256 + lane * 4);
      int sbase = ch * 32 + w * 8;
      const float* ep = enc + ((size_t)sbase * BATCH + b) * HDIM;
      f32x4 cur[4];
      #pragma unroll
      for (int j = 0; j < 4; ++j) cur[j] = *(const f32x4*)(ep + j * 256 + lane * 4);
      float m = -3.0e38f, l = 0.f;
      f32x4 cacc[4] = {{0,0,0,0},{0,0,0,0},{0,0,0,0},{0,0,0,0}};
      #pragma unroll
      for (int i = 0; i < 8; ++i) {
        f32x4 nxt[4];
        if (i < 7) {
          const float* np = ep + (size_t)(i + 1) * (BATCH * HDIM);
          #pragma unroll
          for (int j = 0; j < 4; ++j) nxt[j] = *(const f32x4*)(np + j * 256 + lane * 4);
        }
        float d = 0.f;
        #pragma unroll
        for (int j = 0; j < 4; ++j)
          d += cur[j][0]*uev[j][0] + cur[j][1]*uev[j][1] + cur[j][2]*uev[j][2] + cur[j][3]*uev[j][3];
        #pragma unroll
        for (int off = 32; off >= 1; off >>= 1) d += __shfl_xor(d, off);
        if (lane == 0) e_ws[(size_t)b * S_LEN + sbase + i] = d;
        float mn = fmaxf(m, d);
        float sc = __expf(m - mn);
        float p  = __expf(d - mn);
        l = l * sc + p;
        #pragma unroll
        for (int j = 0; j < 4; ++j) cacc[j] = cacc[j] * sc + p * cur[j];
        m = mn;
        if (i < 7) {
          #pragma unroll
          for (int j = 0; j < 4; ++j) cur[j] = nxt[j];
        }
      }
      float* ls_m = smem + 4096;
      float* ls_l = smem + 4100;
      #pragma unroll
      for (int j = 0; j < 4; ++j)
        *(f32x4*)&smem[w * 1024 + j * 256 + lane * 4] = cacc[j];
      if (lane == 0) { ls_m[w] = m; ls_l[w] = l; }
      __syncthreads();
      float mb = fmaxf(fmaxf(ls_m[0], ls_m[1]), fmaxf(ls_m[2], ls_m[3]));
      float f0 = __expf(ls_m[0] - mb), f1 = __expf(ls_m[1] - mb);
      float f2 = __expf(ls_m[2] - mb), f3 = __expf(ls_m[3] - mb);
      float lb = ls_l[0]*f0 + ls_l[1]*f1 + ls_l[2]*f2 + ls_l[3]*f3;
      int h = tid * 4;
      f32x4 v0 = *(f32x4*)&smem[0 * 1024 + h];
      f32x4 v1 = *(f32x4*)&smem[1 * 1024 + h];
      f32x4 v2 = *(f32x4*)&smem[2 * 1024 + h];
      f32x4 v3 = *(f32x4*)&smem[3 * 1024 + h];
      f32x4 sum = f0*v0 + f1*v1 + f2*v2 + f3*v3;
      *(f32x4*)(ctx_part + (size_t)(b * 32 + ch) * HDIM + h) = sum;
      if (tid == 0) {
        ml_ws[(b * 32 + ch) * 2 + 0] = mb;
        ml_ws[(b * 32 + ch) * 2 + 1] = lb;
      }
    }
    __syncthreads();   // smem reuse guard between repeats
  }
}

// ===== K3: bid<128: softmax combine (b, half); bid in [128,192): LSTM pointwise
__global__ __launch_bounds__(256) void k_mid(const float* __restrict__ e_ws,
                                             const float* __restrict__ ctx_part,
                                             const float* __restrict__ ml_ws,
                                             const float* __restrict__ gates_part,
                                             const float* __restrict__ b_ih,
                                             const float* __restrict__ b_hh,
                                             const float* __restrict__ c0,
                                             float* __restrict__ out_h,
                                             float* __restrict__ out_c,
                                             float* __restrict__ out_attn,
                                             short* __restrict__ xc) {
  int bid = blockIdx.x, tid = threadIdx.x;
  if (bid < 128) {
    int b = bid >> 1, half = bid & 1;
    float mc[32], lc[32], fc[32];
    float mball = -3.0e38f;
    #pragma unroll
    for (int c = 0; c < 32; ++c) {
      mc[c] = ml_ws[(b * 32 + c) * 2 + 0];
      lc[c] = ml_ws[(b * 32 + c) * 2 + 1];
      mball = fmaxf(mball, mc[c]);
    }
    float L = 0.f;
    #pragma unroll
    for (int c = 0; c < 32; ++c) { fc[c] = __expf(mc[c] - mball); L += lc[c] * fc[c]; }
    float invL = 1.f / L;
    if (tid < 128) {
      int h = half * 512 + tid * 4;
      f32x4 csum = {0,0,0,0};
      #pragma unroll
      for (int c = 0; c < 32; ++c) {
        f32x4 vv = *(const f32x4*)(ctx_part + (size_t)(b * 32 + c) * HDIM + h);
        csum += fc[c] * vv;
      }
      csum *= invL;
      bfx4 o;
      o[0] = f2bf(csum[0]); o[1] = f2bf(csum[1]); o[2] = f2bf(csum[2]); o[3] = f2bf(csum[3]);
      *(bfx4*)(xc + (size_t)b * 2048 + HDIM + h) = o;
      int s = half * 512 + tid * 4;
      f32x4 ev = *(const f32x4*)(e_ws + (size_t)b * S_LEN + s);
      f32x4 a;
      a[0] = __expf(ev[0] - mball) * invL; a[1] = __expf(ev[1] - mball) * invL;
      a[2] = __expf(ev[2] - mball) * invL; a[3] = __expf(ev[3] - mball) * invL;
      *(f32x4*)(out_attn + (size_t)b * S_LEN + s) = a;
    }
  } else {
    int ht = bid - 128;
    int b = tid & 63, ho = tid >> 6;
    #pragma unroll
    for (int u = 0; u < 4; ++u) {
      int hi = ht * 16 + u * 4 + ho;
      float g[4];
      #pragma unroll
      for (int ty = 0; ty < 4; ++ty) {
        int r = ty * HDIM + hi;
        float s = b_ih[r] + b_hh[r];
        #pragma unroll
        for (int sl = 0; sl < 4; ++sl) s += gates_part[((size_t)sl * 4096 + r) * 64 + b];
        g[ty] = s;
      }
      float cc = sigmf(g[1]) * c0[(size_t)b * HDIM + hi] + sigmf(g[0]) * tanhf(g[2]);
      float hh = sigmf(g[3]) * tanhf(cc);
      out_h[(size_t)b * HDIM + hi] = hh;
      out_c[(size_t)b * HDIM + hi] = cc;
      xc[(size_t)b * 2048 + hi] = f2bf(hh);
    }
  }
}

// ===== K4: Wal split-K partial: block = (tile, kslice), wave = 128-subslice
__global__ __launch_bounds__(256) void k_walp(const float* __restrict__ Wal,
                                              const short* __restrict__ xc,
                                              float* __restrict__ wal_part) {
  __shared__ float wbuf[4 * 16 * 65];
  int bid = blockIdx.x, tid = threadIdx.x;
  int w = tid >> 6, lane = tid & 63;
  int r_lo = lane & 15, kq8 = (lane >> 4) * 8;
  int tile = bid >> 2, ks = bid & 3;
  int row = tile * 16 + r_lo;
  const float* ar = Wal + (size_t)row * 2048;
  const short* x0 = xc + (size_t)(r_lo) * 2048;
  const short* x1 = xc + (size_t)(16 + r_lo) * 2048;
  const short* x2 = xc + (size_t)(32 + r_lo) * 2048;
  const short* x3 = xc + (size_t)(48 + r_lo) * 2048;
  f32x4 acc0 = {0,0,0,0}, acc1 = {0,0,0,0}, acc2 = {0,0,0,0}, acc3 = {0,0,0,0};
  int kbeg = ks * 512 + w * 128;
  #pragma unroll
  for (int k0 = kbeg; k0 < kbeg + 128; k0 += 32) {
    int k = k0 + kq8;
    f32x4 a0 = *(const f32x4*)(ar + k);
    f32x4 a1 = *(const f32x4*)(ar + k + 4);
    bfx8 af;
    af[0] = f2bf(a0[0]); af[1] = f2bf(a0[1]); af[2] = f2bf(a0[2]); af[3] = f2bf(a0[3]);
    af[4] = f2bf(a1[0]); af[5] = f2bf(a1[1]); af[6] = f2bf(a1[2]); af[7] = f2bf(a1[3]);
    bfx8 b0 = *(const bfx8*)(x0 + k);
    bfx8 b1 = *(const bfx8*)(x1 + k);
    bfx8 b2 = *(const bfx8*)(x2 + k);
    bfx8 b3 = *(const bfx8*)(x3 + k);
    acc0 = __builtin_amdgcn_mfma_f32_16x16x32_bf16(af, b0, acc0, 0, 0, 0);
    acc1 = __builtin_amdgcn_mfma_f32_16x16x32_bf16(af, b1, acc1, 0, 0, 0);
    acc2 = __builtin_amdgcn_mfma_f32_16x16x32_bf16(af, b2, acc2, 0, 0, 0);
    acc3 = __builtin_amdgcn_mfma_f32_16x16x32_bf16(af, b3, acc3, 0, 0, 0);
  }
  int hl4 = 4 * (lane >> 4);
  #pragma unroll
  for (int i = 0; i < 4; ++i) {
    wbuf[(w * 16 + hl4 + i) * 65 +  0 + r_lo] = acc0[i];
    wbuf[(w * 16 + hl4 + i) * 65 + 16 + r_lo] = acc1[i];
    wbuf[(w * 16 + hl4 + i) * 65 + 32 + r_lo] = acc2[i];
    wbuf[(w * 16 + hl4 + i) * 65 + 48 + r_lo] = acc3[i];
  }
  __syncthreads();
  int b = tid & 63, ho = tid >> 6;
  #pragma unroll
  for (int u = 0; u < 4; ++u) {
    int hl = u * 4 + ho;
    float s = wbuf[( 0 + hl) * 65 + b] + wbuf[(16 + hl) * 65 + b]
            + wbuf[(32 + hl) * 65 + b] + wbuf[(48 + hl) * 65 + b];
    wal_part[(size_t)ks * 65536 + (size_t)(tile * 16 + hl) * 64 + b] = s;
  }
}

// ===== K5: tmp = tanh(sum wal_part + bal) -> bf16
__global__ __launch_bounds__(256) void k_walr(const float* __restrict__ wal_part,
                                              const float* __restrict__ bal,
                                              short* __restrict__ tmpb) {
  int t = blockIdx.x * 256 + threadIdx.x;
  int b = t & 63, j = t >> 6;
  float s = bal[j];
  #pragma unroll
  for (int ks = 0; ks < 4; ++ks) s += wal_part[(size_t)ks * 65536 + (size_t)j * 64 + b];
  tmpb[(size_t)b * HDIM + j] = f2bf(tanhf(s));
}

// ===== K6: logits = tmp @ Wout^T + bout (32 rows/block), REP6 probe repeats
__global__ __launch_bounds__(128) void k_logits(const float* __restrict__ Wout,
                                                const short* __restrict__ tmpb,
                                                const float* __restrict__ bout,
                                                float* __restrict__ out) {
  __shared__ float lt[64 * 33];
  int tid = threadIdx.x;
  int w = tid >> 6, lane = tid & 63;
  int r_lo = lane & 15, kq8 = (lane >> 4) * 8;
  int v0 = blockIdx.x * 32;
  for (int rep = 0; rep < REP6; ++rep) {
    int row = v0 + w * 16 + r_lo;
    if (row >= VOCAB) row = VOCAB - 1;
    const float* ar = Wout + (size_t)row * HDIM;
    const short* x0 = tmpb + (size_t)(r_lo) * HDIM;
    const short* x1 = tmpb + (size_t)(16 + r_lo) * HDIM;
    const short* x2 = tmpb + (size_t)(32 + r_lo) * HDIM;
    const short* x3 = tmpb + (size_t)(48 + r_lo) * HDIM;
    f32x4 acc0 = {0,0,0,0}, acc1 = {0,0,0,0}, acc2 = {0,0,0,0}, acc3 = {0,0,0,0};
    #pragma unroll 4
    for (int k0 = 0; k0 < HDIM; k0 += 32) {
      int k = k0 + kq8;
      f32x4 a0 = *(const f32x4*)(ar + k);
      f32x4 a1 = *(const f32x4*)(ar + k + 4);
      bfx8 af;
      af[0] = f2bf(a0[0]); af[1] = f2bf(a0[1]); af[2] = f2bf(a0[2]); af[3] = f2bf(a0[3]);
      af[4] = f2bf(a1[0]); af[5] = f2bf(a1[1]); af[6] = f2bf(a1[2]); af[7] = f2bf(a1[3]);
      bfx8 b0 = *(const bfx8*)(x0 + k);
      bfx8 b1 = *(const bfx8*)(x1 + k);
      bfx8 b2 = *(const bfx8*)(x2 + k);
      bfx8 b3 = *(const bfx8*)(x3 + k);
      acc0 = __builtin_amdgcn_mfma_f32_16x16x32_bf16(af, b0, acc0, 0, 0, 0);
      acc1 = __builtin_amdgcn_mfma_f32_16x16x32_bf16(af, b1, acc1, 0, 0, 0);
      acc2 = __builtin_amdgcn_mfma_f32_16x16x32_bf16(af, b2, acc2, 0, 0, 0);
      acc3 = __builtin_amdgcn_mfma_f32_16x16x32_bf16(af, b3, acc3, 0, 0, 0);
    }
    int vl4 = w * 16 + 4 * (lane >> 4);
    #pragma unroll
    for (int i = 0; i < 4; ++i) {
      lt[( 0 + r_lo) * 33 + vl4 + i] = acc0[i];
      lt[(16 + r_lo) * 33 + vl4 + i] = acc1[i];
      lt[(32 + r_lo) * 33 + vl4 + i] = acc2[i];
      lt[(48 + r_lo) * 33 + vl4 + i] = acc3[i];
    }
    __syncthreads();
    int vloc = tid & 31, bq = tid >> 5;
    int v = v0 + vloc;
    if (v < VOCAB) {
      float bo = bout[v];
      #pragma unroll
      for (int q = 0; q < 16; ++q) {
        int b = bq * 16 + q;
        out[(size_t)b * VOCAB + v] = lt[b * 33 + vloc] + bo;
      }
    }
    __syncthreads();   // LDS reuse guard between repeats
  }
}

extern "C" void kernel_launch(void* const* d_in, const int* in_sizes, int n_in,
                              void* d_out, int out_size, void* d_ws, size_t ws_size,
                              hipStream_t stream) {
  const float* enc   = (const float*)d_in[0];
  const int*   seq   = (const int*)  d_in[1];
  const float* h0    = (const float*)d_in[2];
  const float* c0    = (const float*)d_in[3];
  const float* embed = (const float*)d_in[4];
  const float* W_ih  = (const float*)d_in[5];
  const float* W_hh  = (const float*)d_in[6];
  const float* b_ih  = (const float*)d_in[7];
  const float* b_hh  = (const float*)d_in[8];
  const float* Wa    = (const float*)d_in[9];
  // d_in[10] = ba: cancels in softmax, unused
  const float* vvec  = (const float*)d_in[11];
  const float* Wal   = (const float*)d_in[12];
  const float* bal   = (const float*)d_in[13];
  const float* Wout  = (const float*)d_in[14];
  const float* bout  = (const float*)d_in[15];

  float* out        = (float*)d_out;
  float* out_h      = out + (size_t)BATCH * VOCAB;
  float* out_c      = out_h + BATCH * HDIM;
  float* out_attn   = out_c + BATCH * HDIM;

  float* ws         = (float*)d_ws;
  float* ue         = ws;                           // 1024
  float* e_ws       = ue + 1024;                    // 64*1024
  float* ml_ws      = e_ws + 65536;                 // 64*32*2 = 4096
  float* ctx_part   = ml_ws + 4096;                 // 64*32*1024 = 2097152
  float* gates_part = ctx_part + 2097152;           // 4*4096*64 = 1048576
  float* wal_part   = gates_part + 1048576;         // 4*1024*64 = 262144
  short* xh         = (short*)(wal_part + 262144);  // 64*2048 bf16
  short* xc         = xh + 131072;                  // 64*2048 bf16
  short* tmpb       = xc + 131072;                  // 64*1024 bf16

  k_prep<<<192, 256, 0, stream>>>(seq, embed, h0, Wa, vvec, xh, ue);
  k_big<<<2304, 256, 0, stream>>>(enc, ue, W_ih, W_hh, xh,
                                  gates_part, e_ws, ml_ws, ctx_part);
  k_mid<<<192, 256, 0, stream>>>(e_ws, ctx_part, ml_ws, gates_part, b_ih, b_hh, c0,
                                 out_h, out_c, out_attn, xc);
  k_walp<<<256, 256, 0, stream>>>(Wal, xc, wal_part);
  k_walr<<<256, 256, 0, stream>>>(wal_part, bal, tmpb);
  k_logits<<<1571, 128, 0, stream>>>(Wout, tmpb, bout, out);
}

// Round 6
// 181.822 us; speedup vs baseline: 3.3683x; 3.3683x over previous
//
#include <hip/hip_runtime.h>
#include <hip/hip_bf16.h>
#include <stdint.h>

#define S_LEN 1024
#define BATCH 64
#define HDIM  1024
#define VOCAB 50257

using f32x4 = __attribute__((ext_vector_type(4))) float;
using bfx8  = __attribute__((ext_vector_type(8))) short;
using bfx4  = __attribute__((ext_vector_type(4))) short;

__device__ __forceinline__ short f2bf(float f) {
  uint32_t u = __float_as_uint(f);
  u += 0x7fffu + ((u >> 16) & 1u);   // RNE
  return (short)(u >> 16);
}
__device__ __forceinline__ float sigmf(float x) { return 1.f / (1.f + __expf(-x)); }

// ===== K1: bid<128: xh = [embed[seq[b]] | h0[b]] bf16 ; bid in [128,192): ue
__global__ __launch_bounds__(256) void k_prep(const int* __restrict__ seq,
                                              const float* __restrict__ embed,
                                              const float* __restrict__ h0,
                                              const float* __restrict__ Wa,
                                              const float* __restrict__ vvec,
                                              short* __restrict__ xh,
                                              float* __restrict__ ue) {
  __shared__ float lds[256];
  int bid = blockIdx.x, tid = threadIdx.x;
  if (bid < 128) {
    int b = bid >> 1, half = bid & 1;
    int k = tid * 4;
    const float* src = half ? (h0 + (size_t)b * HDIM + k)
                            : (embed + (size_t)seq[b] * HDIM + k);
    f32x4 v = *(const f32x4*)src;
    bfx4 o;
    o[0] = f2bf(v[0]); o[1] = f2bf(v[1]); o[2] = f2bf(v[2]); o[3] = f2bf(v[3]);
    *(bfx4*)(xh + (size_t)b * 2048 + half * HDIM + k) = o;
  } else {
    int ktile = bid - 128;              // 0..63, 16 k-cols each
    int kc = tid & 15, hc = tid >> 4;   // 16 h-chunks of 64
    int k = ktile * 16 + kc;
    const float* wp = Wa + (size_t)(hc * 64) * 2048 + HDIM + k;
    float acc = 0.f;
    #pragma unroll 4
    for (int i = 0; i < 64; ++i)
      acc += vvec[hc * 64 + i] * wp[(size_t)i * 2048];
    lds[hc * 16 + kc] = acc;
    __syncthreads();
    if (hc == 0) {
      float s = 0.f;
      #pragma unroll
      for (int c = 0; c < 16; ++c) s += lds[c * 16 + kc];
      ue[k] = s;
    }
  }
}

// ===== K2: bid<256: gates split-K partial; bid>=256: attention (2048 items)
__global__ __launch_bounds__(256) void k_big(const float* __restrict__ enc,
                                             const float* __restrict__ ue,
                                             const float* __restrict__ W_ih,
                                             const float* __restrict__ W_hh,
                                             const short* __restrict__ xh,
                                             float* __restrict__ gates_part,
                                             float* __restrict__ e_ws,
                                             float* __restrict__ ml_ws,
                                             float* __restrict__ ctx_part) {
  __shared__ float smem[4160];
  int bid = blockIdx.x, tid = threadIdx.x;
  int w = tid >> 6, lane = tid & 63;
  int r_lo = lane & 15, kq8 = (lane >> 4) * 8;
  if (bid < 256) {
    // gates partial: block = (h-tile, k-slice); wave = gate
    int ht = bid >> 2, ks = bid & 3;
    int row = w * HDIM + ht * 16 + r_lo;
    const float* a0r = W_ih + (size_t)row * HDIM;
    const float* a1r = W_hh + (size_t)row * HDIM - HDIM;
    const short* x0 = xh + (size_t)(r_lo) * 2048;
    const short* x1 = xh + (size_t)(16 + r_lo) * 2048;
    const short* x2 = xh + (size_t)(32 + r_lo) * 2048;
    const short* x3 = xh + (size_t)(48 + r_lo) * 2048;
    f32x4 acc0 = {0,0,0,0}, acc1 = {0,0,0,0}, acc2 = {0,0,0,0}, acc3 = {0,0,0,0};
    int kbeg = ks * 512;
    #pragma unroll 4
    for (int k0 = kbeg; k0 < kbeg + 512; k0 += 32) {
      int k = k0 + kq8;
      const float* ap = (k < HDIM) ? (a0r + k) : (a1r + k);
      f32x4 a0 = *(const f32x4*)ap;
      f32x4 a1 = *(const f32x4*)(ap + 4);
      bfx8 af;
      af[0] = f2bf(a0[0]); af[1] = f2bf(a0[1]); af[2] = f2bf(a0[2]); af[3] = f2bf(a0[3]);
      af[4] = f2bf(a1[0]); af[5] = f2bf(a1[1]); af[6] = f2bf(a1[2]); af[7] = f2bf(a1[3]);
      bfx8 b0 = *(const bfx8*)(x0 + k);
      bfx8 b1 = *(const bfx8*)(x1 + k);
      bfx8 b2 = *(const bfx8*)(x2 + k);
      bfx8 b3 = *(const bfx8*)(x3 + k);
      acc0 = __builtin_amdgcn_mfma_f32_16x16x32_bf16(af, b0, acc0, 0, 0, 0);
      acc1 = __builtin_amdgcn_mfma_f32_16x16x32_bf16(af, b1, acc1, 0, 0, 0);
      acc2 = __builtin_amdgcn_mfma_f32_16x16x32_bf16(af, b2, acc2, 0, 0, 0);
      acc3 = __builtin_amdgcn_mfma_f32_16x16x32_bf16(af, b3, acc3, 0, 0, 0);
    }
    int hl4 = 4 * (lane >> 4);
    #pragma unroll
    for (int i = 0; i < 4; ++i) {
      float* p = gates_part + (size_t)ks * (4096 * 64)
               + (size_t)(w * 1024 + ht * 16 + hl4 + i) * 64;
      p[ 0 + r_lo] = acc0[i];
      p[16 + r_lo] = acc1[i];
      p[32 + r_lo] = acc2[i];
      p[48 + r_lo] = acc3[i];
    }
  } else {
    // attention item: (b, chunk of 32 s-rows), 8 rows per wave, reg prefetch
    int it = bid - 256;
    int b = it & 63, ch = it >> 6;
    f32x4 uev[4];
    #pragma unroll
    for (int j = 0; j < 4; ++j) uev[j] = *(const f32x4*)(ue + j * 256 + lane * 4);
    int sbase = ch * 32 + w * 8;
    const float* ep = enc + ((size_t)sbase * BATCH + b) * HDIM;
    f32x4 cur[4];
    #pragma unroll
    for (int j = 0; j < 4; ++j) cur[j] = *(const f32x4*)(ep + j * 256 + lane * 4);
    float m = -3.0e38f, l = 0.f;
    f32x4 cacc[4] = {{0,0,0,0},{0,0,0,0},{0,0,0,0},{0,0,0,0}};
    #pragma unroll
    for (int i = 0; i < 8; ++i) {
      f32x4 nxt[4];
      if (i < 7) {
        const float* np = ep + (size_t)(i + 1) * (BATCH * HDIM);
        #pragma unroll
        for (int j = 0; j < 4; ++j) nxt[j] = *(const f32x4*)(np + j * 256 + lane * 4);
      }
      float d = 0.f;
      #pragma unroll
      for (int j = 0; j < 4; ++j)
        d += cur[j][0]*uev[j][0] + cur[j][1]*uev[j][1] + cur[j][2]*uev[j][2] + cur[j][3]*uev[j][3];
      #pragma unroll
      for (int off = 32; off >= 1; off >>= 1) d += __shfl_xor(d, off);
      if (lane == 0) e_ws[(size_t)b * S_LEN + sbase + i] = d;
      float mn = fmaxf(m, d);
      float sc = __expf(m - mn);
      float p  = __expf(d - mn);
      l = l * sc + p;
      #pragma unroll
      for (int j = 0; j < 4; ++j) cacc[j] = cacc[j] * sc + p * cur[j];
      m = mn;
      if (i < 7) {
        #pragma unroll
        for (int j = 0; j < 4; ++j) cur[j] = nxt[j];
      }
    }
    float* ls_m = smem + 4096;
    float* ls_l = smem + 4100;
    #pragma unroll
    for (int j = 0; j < 4; ++j)
      *(f32x4*)&smem[w * 1024 + j * 256 + lane * 4] = cacc[j];
    if (lane == 0) { ls_m[w] = m; ls_l[w] = l; }
    __syncthreads();
    float mb = fmaxf(fmaxf(ls_m[0], ls_m[1]), fmaxf(ls_m[2], ls_m[3]));
    float f0 = __expf(ls_m[0] - mb), f1 = __expf(ls_m[1] - mb);
    float f2 = __expf(ls_m[2] - mb), f3 = __expf(ls_m[3] - mb);
    float lb = ls_l[0]*f0 + ls_l[1]*f1 + ls_l[2]*f2 + ls_l[3]*f3;
    int h = tid * 4;
    f32x4 v0 = *(f32x4*)&smem[0 * 1024 + h];
    f32x4 v1 = *(f32x4*)&smem[1 * 1024 + h];
    f32x4 v2 = *(f32x4*)&smem[2 * 1024 + h];
    f32x4 v3 = *(f32x4*)&smem[3 * 1024 + h];
    f32x4 sum = f0*v0 + f1*v1 + f2*v2 + f3*v3;
    *(f32x4*)(ctx_part + (size_t)(b * 32 + ch) * HDIM + h) = sum;
    if (tid == 0) {
      ml_ws[(b * 32 + ch) * 2 + 0] = mb;
      ml_ws[(b * 32 + ch) * 2 + 1] = lb;
    }
  }
}

// ===== K3: bid<128: softmax combine (b, half); bid in [128,192): LSTM pointwise
__global__ __launch_bounds__(256) void k_mid(const float* __restrict__ e_ws,
                                             const float* __restrict__ ctx_part,
                                             const float* __restrict__ ml_ws,
                                             const float* __restrict__ gates_part,
                                             const float* __restrict__ b_ih,
                                             const float* __restrict__ b_hh,
                                             const float* __restrict__ c0,
                                             float* __restrict__ out_h,
                                             float* __restrict__ out_c,
                                             float* __restrict__ out_attn,
                                             short* __restrict__ xc) {
  int bid = blockIdx.x, tid = threadIdx.x;
  if (bid < 128) {
    int b = bid >> 1, half = bid & 1;
    float mc[32], lc[32], fc[32];
    float mball = -3.0e38f;
    #pragma unroll
    for (int c = 0; c < 32; ++c) {
      mc[c] = ml_ws[(b * 32 + c) * 2 + 0];
      lc[c] = ml_ws[(b * 32 + c) * 2 + 1];
      mball = fmaxf(mball, mc[c]);
    }
    float L = 0.f;
    #pragma unroll
    for (int c = 0; c < 32; ++c) { fc[c] = __expf(mc[c] - mball); L += lc[c] * fc[c]; }
    float invL = 1.f / L;
    if (tid < 128) {
      int h = half * 512 + tid * 4;
      f32x4 csum = {0,0,0,0};
      #pragma unroll
      for (int c = 0; c < 32; ++c) {
        f32x4 vv = *(const f32x4*)(ctx_part + (size_t)(b * 32 + c) * HDIM + h);
        csum += fc[c] * vv;
      }
      csum *= invL;
      bfx4 o;
      o[0] = f2bf(csum[0]); o[1] = f2bf(csum[1]); o[2] = f2bf(csum[2]); o[3] = f2bf(csum[3]);
      *(bfx4*)(xc + (size_t)b * 2048 + HDIM + h) = o;
      int s = half * 512 + tid * 4;
      f32x4 ev = *(const f32x4*)(e_ws + (size_t)b * S_LEN + s);
      f32x4 a;
      a[0] = __expf(ev[0] - mball) * invL; a[1] = __expf(ev[1] - mball) * invL;
      a[2] = __expf(ev[2] - mball) * invL; a[3] = __expf(ev[3] - mball) * invL;
      *(f32x4*)(out_attn + (size_t)b * S_LEN + s) = a;
    }
  } else {
    int ht = bid - 128;
    int b = tid & 63, ho = tid >> 6;
    #pragma unroll
    for (int u = 0; u < 4; ++u) {
      int hi = ht * 16 + u * 4 + ho;
      float g[4];
      #pragma unroll
      for (int ty = 0; ty < 4; ++ty) {
        int r = ty * HDIM + hi;
        float s = b_ih[r] + b_hh[r];
        #pragma unroll
        for (int sl = 0; sl < 4; ++sl) s += gates_part[((size_t)sl * 4096 + r) * 64 + b];
        g[ty] = s;
      }
      float cc = sigmf(g[1]) * c0[(size_t)b * HDIM + hi] + sigmf(g[0]) * tanhf(g[2]);
      float hh = sigmf(g[3]) * tanhf(cc);
      out_h[(size_t)b * HDIM + hi] = hh;
      out_c[(size_t)b * HDIM + hi] = cc;
      xc[(size_t)b * 2048 + hi] = f2bf(hh);
    }
  }
}

// ===== K4: Wal split-K partial: block = (tile, kslice), wave = 128-subslice
__global__ __launch_bounds__(256) void k_walp(const float* __restrict__ Wal,
                                              const short* __restrict__ xc,
                                              float* __restrict__ wal_part) {
  __shared__ float wbuf[4 * 16 * 65];
  int bid = blockIdx.x, tid = threadIdx.x;
  int w = tid >> 6, lane = tid & 63;
  int r_lo = lane & 15, kq8 = (lane >> 4) * 8;
  int tile = bid >> 2, ks = bid & 3;
  int row = tile * 16 + r_lo;
  const float* ar = Wal + (size_t)row * 2048;
  const short* x0 = xc + (size_t)(r_lo) * 2048;
  const short* x1 = xc + (size_t)(16 + r_lo) * 2048;
  const short* x2 = xc + (size_t)(32 + r_lo) * 2048;
  const short* x3 = xc + (size_t)(48 + r_lo) * 2048;
  f32x4 acc0 = {0,0,0,0}, acc1 = {0,0,0,0}, acc2 = {0,0,0,0}, acc3 = {0,0,0,0};
  int kbeg = ks * 512 + w * 128;
  #pragma unroll
  for (int k0 = kbeg; k0 < kbeg + 128; k0 += 32) {
    int k = k0 + kq8;
    f32x4 a0 = *(const f32x4*)(ar + k);
    f32x4 a1 = *(const f32x4*)(ar + k + 4);
    bfx8 af;
    af[0] = f2bf(a0[0]); af[1] = f2bf(a0[1]); af[2] = f2bf(a0[2]); af[3] = f2bf(a0[3]);
    af[4] = f2bf(a1[0]); af[5] = f2bf(a1[1]); af[6] = f2bf(a1[2]); af[7] = f2bf(a1[3]);
    bfx8 b0 = *(const bfx8*)(x0 + k);
    bfx8 b1 = *(const bfx8*)(x1 + k);
    bfx8 b2 = *(const bfx8*)(x2 + k);
    bfx8 b3 = *(const bfx8*)(x3 + k);
    acc0 = __builtin_amdgcn_mfma_f32_16x16x32_bf16(af, b0, acc0, 0, 0, 0);
    acc1 = __builtin_amdgcn_mfma_f32_16x16x32_bf16(af, b1, acc1, 0, 0, 0);
    acc2 = __builtin_amdgcn_mfma_f32_16x16x32_bf16(af, b2, acc2, 0, 0, 0);
    acc3 = __builtin_amdgcn_mfma_f32_16x16x32_bf16(af, b3, acc3, 0, 0, 0);
  }
  int hl4 = 4 * (lane >> 4);
  #pragma unroll
  for (int i = 0; i < 4; ++i) {
    wbuf[(w * 16 + hl4 + i) * 65 +  0 + r_lo] = acc0[i];
    wbuf[(w * 16 + hl4 + i) * 65 + 16 + r_lo] = acc1[i];
    wbuf[(w * 16 + hl4 + i) * 65 + 32 + r_lo] = acc2[i];
    wbuf[(w * 16 + hl4 + i) * 65 + 48 + r_lo] = acc3[i];
  }
  __syncthreads();
  int b = tid & 63, ho = tid >> 6;
  #pragma unroll
  for (int u = 0; u < 4; ++u) {
    int hl = u * 4 + ho;
    float s = wbuf[( 0 + hl) * 65 + b] + wbuf[(16 + hl) * 65 + b]
            + wbuf[(32 + hl) * 65 + b] + wbuf[(48 + hl) * 65 + b];
    wal_part[(size_t)ks * 65536 + (size_t)(tile * 16 + hl) * 64 + b] = s;
  }
}

// ===== K5: tmp = tanh(sum wal_part + bal) -> bf16
__global__ __launch_bounds__(256) void k_walr(const float* __restrict__ wal_part,
                                              const float* __restrict__ bal,
                                              short* __restrict__ tmpb) {
  int t = blockIdx.x * 256 + threadIdx.x;
  int b = t & 63, j = t >> 6;
  float s = bal[j];
  #pragma unroll
  for (int ks = 0; ks < 4; ++ks) s += wal_part[(size_t)ks * 65536 + (size_t)j * 64 + b];
  tmpb[(size_t)b * HDIM + j] = f2bf(tanhf(s));
}

// ===== K6: logits = tmp @ Wout^T + bout
// 256 threads / 32 rows per block; wave w: rows (w&1)*16, K-slice (w>>1)*512.
// Explicit A-prefetch; LDS combine of the 2 K-slices. No reg cap.
__global__ __launch_bounds__(256) void k_logits(const float* __restrict__ Wout,
                                                const short* __restrict__ tmpb,
                                                const float* __restrict__ bout,
                                                float* __restrict__ out) {
  __shared__ float lt[2][64][33];
  int tid = threadIdx.x;
  int w = tid >> 6, lane = tid & 63;
  int r_lo = lane & 15, kq8 = (lane >> 4) * 8;
  int v0 = blockIdx.x * 32;
  int rowgrp = w & 1, ks = w >> 1;
  int row = v0 + rowgrp * 16 + r_lo;
  if (row >= VOCAB) row = VOCAB - 1;
  const float* ar = Wout + (size_t)row * HDIM + ks * 512;
  const short* xb = tmpb + ks * 512;
  const short* x0 = xb + (size_t)(r_lo) * HDIM;
  const short* x1 = xb + (size_t)(16 + r_lo) * HDIM;
  const short* x2 = xb + (size_t)(32 + r_lo) * HDIM;
  const short* x3 = xb + (size_t)(48 + r_lo) * HDIM;
  f32x4 acc0 = {0,0,0,0}, acc1 = {0,0,0,0}, acc2 = {0,0,0,0}, acc3 = {0,0,0,0};
  f32x4 ca0 = *(const f32x4*)(ar + kq8);
  f32x4 ca1 = *(const f32x4*)(ar + kq8 + 4);
  #pragma unroll
  for (int s = 0; s < 16; ++s) {
    f32x4 na0, na1;
    if (s < 15) {
      na0 = *(const f32x4*)(ar + (s + 1) * 32 + kq8);
      na1 = *(const f32x4*)(ar + (s + 1) * 32 + kq8 + 4);
    }
    bfx8 af;
    af[0] = f2bf(ca0[0]); af[1] = f2bf(ca0[1]); af[2] = f2bf(ca0[2]); af[3] = f2bf(ca0[3]);
    af[4] = f2bf(ca1[0]); af[5] = f2bf(ca1[1]); af[6] = f2bf(ca1[2]); af[7] = f2bf(ca1[3]);
    int k = s * 32 + kq8;
    bfx8 b0 = *(const bfx8*)(x0 + k);
    bfx8 b1 = *(const bfx8*)(x1 + k);
    bfx8 b2 = *(const bfx8*)(x2 + k);
    bfx8 b3 = *(const bfx8*)(x3 + k);
    acc0 = __builtin_amdgcn_mfma_f32_16x16x32_bf16(af, b0, acc0, 0, 0, 0);
    acc1 = __builtin_amdgcn_mfma_f32_16x16x32_bf16(af, b1, acc1, 0, 0, 0);
    acc2 = __builtin_amdgcn_mfma_f32_16x16x32_bf16(af, b2, acc2, 0, 0, 0);
    acc3 = __builtin_amdgcn_mfma_f32_16x16x32_bf16(af, b3, acc3, 0, 0, 0);
    if (s < 15) { ca0 = na0; ca1 = na1; }
  }
  int vl = rowgrp * 16 + 4 * (lane >> 4);
  #pragma unroll
  for (int i = 0; i < 4; ++i) {
    lt[ks][ 0 + r_lo][vl + i] = acc0[i];
    lt[ks][16 + r_lo][vl + i] = acc1[i];
    lt[ks][32 + r_lo][vl + i] = acc2[i];
    lt[ks][48 + r_lo][vl + i] = acc3[i];
  }
  __syncthreads();
  int vloc = tid & 31, b8 = (tid >> 5) * 8;
  int v = v0 + vloc;
  if (v < VOCAB) {
    float bo = bout[v];
    #pragma unroll
    for (int q = 0; q < 8; ++q) {
      int b = b8 + q;
      out[(size_t)b * VOCAB + v] = lt[0][b][vloc] + lt[1][b][vloc] + bo;
    }
  }
}

extern "C" void kernel_launch(void* const* d_in, const int* in_sizes, int n_in,
                              void* d_out, int out_size, void* d_ws, size_t ws_size,
                              hipStream_t stream) {
  const float* enc   = (const float*)d_in[0];
  const int*   seq   = (const int*)  d_in[1];
  const float* h0    = (const float*)d_in[2];
  const float* c0    = (const float*)d_in[3];
  const float* embed = (const float*)d_in[4];
  const float* W_ih  = (const float*)d_in[5];
  const float* W_hh  = (const float*)d_in[6];
  const float* b_ih  = (const float*)d_in[7];
  const float* b_hh  = (const float*)d_in[8];
  const float* Wa    = (const float*)d_in[9];
  // d_in[10] = ba: cancels in softmax, unused
  const float* vvec  = (const float*)d_in[11];
  const float* Wal   = (const float*)d_in[12];
  const float* bal   = (const float*)d_in[13];
  const float* Wout  = (const float*)d_in[14];
  const float* bout  = (const float*)d_in[15];

  float* out        = (float*)d_out;
  float* out_h      = out + (size_t)BATCH * VOCAB;
  float* out_c      = out_h + BATCH * HDIM;
  float* out_attn   = out_c + BATCH * HDIM;

  float* ws         = (float*)d_ws;
  float* ue         = ws;                           // 1024
  float* e_ws       = ue + 1024;                    // 64*1024
  float* ml_ws      = e_ws + 65536;                 // 64*32*2 = 4096
  float* ctx_part   = ml_ws + 4096;                 // 64*32*1024 = 2097152
  float* gates_part = ctx_part + 2097152;           // 4*4096*64 = 1048576
  float* wal_part   = gates_part + 1048576;         // 4*1024*64 = 262144
  short* xh         = (short*)(wal_part + 262144);  // 64*2048 bf16
  short* xc         = xh + 131072;                  // 64*2048 bf16
  short* tmpb       = xc + 131072;                  // 64*1024 bf16

  k_prep<<<192, 256, 0, stream>>>(seq, embed, h0, Wa, vvec, xh, ue);
  k_big<<<2304, 256, 0, stream>>>(enc, ue, W_ih, W_hh, xh,
                                  gates_part, e_ws, ml_ws, ctx_part);
  k_mid<<<192, 256, 0, stream>>>(e_ws, ctx_part, ml_ws, gates_part, b_ih, b_hh, c0,
                                 out_h, out_c, out_attn, xc);
  k_walp<<<256, 256, 0, stream>>>(Wal, xc, wal_part);
  k_walr<<<256, 256, 0, stream>>>(wal_part, bal, tmpb);
  k_logits<<<1571, 256, 0, stream>>>(Wout, tmpb, bout, out);
}